// Round 9
// baseline (262.031 us; speedup 1.0000x reference)
//
#include <hip/hip_runtime.h>
#include <math.h>
#include <string.h>

// RX gate on qubit 5 of 12, batch 4096 states of dim 4096.
// out_re[i] = c*sr[i] + s*si[i^64];  out_im[i] = c*si[i] - s*sr[i^64]
//
// v9: CONTROL ROUND (deliberate dur_us regression). 8 rounds of evidence:
// five structurally independent kernels + full NT/plain cache-policy matrix
// all converge at ~66us = 4.06 TB/s mixed 2R+2W (traffic compulsory-exact).
// Before declaring that the environment's mixed-stream ceiling, rule 10
// demands an external known-good under the SAME conditions. So: enqueue a
// vendor D2D copy (hipMemcpyAsync x2 = 134MB R + 134MB W, the kernel's
// exact traffic mix) BEFORE the real kernel on the same stream. The copy
// scribbles on d_out; the kernel (v5 verbatim, best: ~66us) then overwrites
// every byte with correct results -> bench passes. The copy's cost = total
// minus the known 226us baseline, and its rocprof row shows its achieved
// hbm_gbps directly.
//   increment ~43us (>=5.6 TB/s): headroom exists -> clone the copy's shape.
//   increment ~66us (~4 TB/s): vendor copy == our kernel -> ROOFLINE proven.

#define NQ_N 4096
#define NQ_BATCH 4096

typedef float f32x4 __attribute__((ext_vector_type(4)));

#define TOTAL_PAIRS (1u << 21)
#define PAIR_OFFSET (1u << 20)

__global__ __launch_bounds__(256)
void rx_nt_kernel(const f32x4* __restrict__ sr,
                  const f32x4* __restrict__ si,
                  const float* __restrict__ theta_p,
                  f32x4* __restrict__ out_re,
                  f32x4* __restrict__ out_im)
{
    const float half = 0.5f * theta_p[0];
    const float c = cosf(half);
    const float s = sinf(half);

    const unsigned u = blockIdx.x * blockDim.x + threadIdx.x;

    const unsigned p0 = u;
    const unsigned p1 = u + PAIR_OFFSET;

    const unsigned i0 = p0 + (p0 & ~15u);
    const unsigned j0 = i0 + 16;
    const unsigned i1 = p1 + (p1 & ~15u);
    const unsigned j1 = i1 + 16;

    const f32x4 rA = __builtin_nontemporal_load(sr + i0);
    const f32x4 rB = __builtin_nontemporal_load(sr + j0);
    const f32x4 mA = __builtin_nontemporal_load(si + i0);
    const f32x4 mB = __builtin_nontemporal_load(si + j0);
    const f32x4 rC = __builtin_nontemporal_load(sr + i1);
    const f32x4 rD = __builtin_nontemporal_load(sr + j1);
    const f32x4 mC = __builtin_nontemporal_load(si + i1);
    const f32x4 mD = __builtin_nontemporal_load(si + j1);

    f32x4 reA, imA, reB, imB, reC, imC, reD, imD;
#pragma unroll
    for (int k = 0; k < 4; ++k) {
        reA[k] = fmaf(c, rA[k],  s * mB[k]);
        imA[k] = fmaf(c, mA[k], -s * rB[k]);
        reB[k] = fmaf(c, rB[k],  s * mA[k]);
        imB[k] = fmaf(c, mB[k], -s * rA[k]);
        reC[k] = fmaf(c, rC[k],  s * mD[k]);
        imC[k] = fmaf(c, mC[k], -s * rD[k]);
        reD[k] = fmaf(c, rD[k],  s * mC[k]);
        imD[k] = fmaf(c, mD[k], -s * rC[k]);
    }

    __builtin_nontemporal_store(reA, out_re + i0);
    __builtin_nontemporal_store(imA, out_im + i0);
    __builtin_nontemporal_store(reB, out_re + j0);
    __builtin_nontemporal_store(imB, out_im + j0);
    __builtin_nontemporal_store(reC, out_re + i1);
    __builtin_nontemporal_store(imC, out_im + i1);
    __builtin_nontemporal_store(reD, out_re + j1);
    __builtin_nontemporal_store(imD, out_im + j1);
}

extern "C" void kernel_launch(void* const* d_in, const int* in_sizes, int n_in,
                              void* d_out, int out_size, void* d_ws, size_t ws_size,
                              hipStream_t stream)
{
    const f32x4* sr = (const f32x4*)d_in[0];
    const f32x4* si = (const f32x4*)d_in[1];
    const float* th = (const float*)d_in[2];

    f32x4* out_re = (f32x4*)d_out;
    f32x4* out_im = out_re + ((size_t)NQ_BATCH * NQ_N / 4);

    // ---- CONTROL: vendor D2D copy, exact same traffic mix (134MB R+W).
    // Stream-ordered BEFORE the kernel; kernel overwrites every byte, so
    // final output is correct. hipMemcpyAsync on the capture stream is
    // graph-capture-legal (G9).
    const size_t half_bytes = (size_t)NQ_BATCH * NQ_N * sizeof(float); // 67.1MB
    hipMemcpyAsync(out_re, sr, half_bytes, hipMemcpyDeviceToDevice, stream);
    hipMemcpyAsync(out_im, si, half_bytes, hipMemcpyDeviceToDevice, stream);

    // ---- Real kernel (v5 verbatim, best known: ~66us)
    const unsigned threads = TOTAL_PAIRS / 2;
    const unsigned block = 256;
    const unsigned grid = threads / block;

    rx_nt_kernel<<<grid, block, 0, stream>>>(sr, si, th, out_re, out_im);
}

// Round 10
// 227.108 us; speedup vs baseline: 1.1538x; 1.1538x over previous
//
#include <hip/hip_runtime.h>
#include <math.h>

// RX gate on qubit 5 of 12, batch 4096 states of dim 4096.
// out_re[i] = c*sr[i] + s*si[i^64];  out_im[i] = c*si[i] - s*sr[i^64]
// (M = c*I - i*s*X_hyd is symmetric; X_hyd is the bit-6 flip permutation.)
//
// v10: clone the CONCURRENCY SHAPE of the in-harness known-goods.
// Evidence: harness fills hit 6.7 TB/s at ~3 waves/CU with long sequential
// per-thread runs; v9's hipMemcpyAsync control moved our exact traffic mix
// at ~7 TB/s. Every kernel v1-v8 ran 16-32 waves/CU with <=8 short rounds
// and capped at ~4 TB/s regardless of structure/cache policy/scope -> the
// one untested dimension is stream multiplicity: thousands of short-lived
// read streams thrash DRAM row buffers; writes don't care (fills prove it).
// Shape here: 512 blocks (8 waves/CU), block owns a CONTIGUOUS 4096-pair
// region, 16 rounds/thread, depth-2 pipeline (next round's 4 NT loads in
// flight under current round's compute+store). In-flight = 8 waves x 4KB
// = 32KB/CU >> 9.2KB Little's-law minimum, so latency stays hidden.
// NT loads (v5's +14us, keep) + NT stores.

#define NQ_N 4096
#define NQ_BATCH 4096

typedef float f32x4 __attribute__((ext_vector_type(4)));

#define BLK 256u
#define GRID 512u
#define ROUNDS 16u
#define PAIRS_PER_BLOCK (BLK * ROUNDS)   // 4096 contiguous pairs per block
// total pairs = 512 * 4096 = 2^21  (= 2^22 f32x4 vecs / 2)

__global__ __launch_bounds__(BLK)
void rx_fillshape_kernel(const f32x4* __restrict__ sr,
                         const f32x4* __restrict__ si,
                         const float* __restrict__ theta_p,
                         f32x4* __restrict__ out_re,
                         f32x4* __restrict__ out_im)
{
    const float half = 0.5f * theta_p[0];
    const float c = cosf(half);
    const float s = sinf(half);

    // block-contiguous pair region; round k handles pair pb + k*256
    const unsigned pb = blockIdx.x * PAIRS_PER_BLOCK + threadIdx.x;

    // prologue: round-0 indices + loads
    unsigned i0, j0;
    {
        const unsigned p = pb;
        i0 = p + (p & ~15u);      // vec index with bit4 forced to 0
        j0 = i0 + 16u;
    }
    f32x4 rA = __builtin_nontemporal_load(sr + i0);
    f32x4 rB = __builtin_nontemporal_load(sr + j0);
    f32x4 mA = __builtin_nontemporal_load(si + i0);
    f32x4 mB = __builtin_nontemporal_load(si + j0);

#pragma unroll
    for (unsigned k = 0; k < ROUNDS; ++k) {
        // issue next round's loads BEFORE consuming this round's data
        unsigned i1 = 0, j1 = 0;
        f32x4 rA1, rB1, mA1, mB1;
        if (k + 1 < ROUNDS) {
            const unsigned p = pb + (k + 1) * BLK;
            i1 = p + (p & ~15u);
            j1 = i1 + 16u;
            rA1 = __builtin_nontemporal_load(sr + i1);
            rB1 = __builtin_nontemporal_load(sr + j1);
            mA1 = __builtin_nontemporal_load(si + i1);
            mB1 = __builtin_nontemporal_load(si + j1);
        }

        f32x4 reA, imA, reB, imB;
#pragma unroll
        for (int q = 0; q < 4; ++q) {
            reA[q] = fmaf(c, rA[q],  s * mB[q]);
            imA[q] = fmaf(c, mA[q], -s * rB[q]);
            reB[q] = fmaf(c, rB[q],  s * mA[q]);
            imB[q] = fmaf(c, mB[q], -s * rA[q]);
        }

        __builtin_nontemporal_store(reA, out_re + i0);
        __builtin_nontemporal_store(imA, out_im + i0);
        __builtin_nontemporal_store(reB, out_re + j0);
        __builtin_nontemporal_store(imB, out_im + j0);

        // rotate pipeline registers
        i0 = i1; j0 = j1;
        rA = rA1; rB = rB1; mA = mA1; mB = mB1;
    }
}

extern "C" void kernel_launch(void* const* d_in, const int* in_sizes, int n_in,
                              void* d_out, int out_size, void* d_ws, size_t ws_size,
                              hipStream_t stream)
{
    const f32x4* sr = (const f32x4*)d_in[0];
    const f32x4* si = (const f32x4*)d_in[1];
    const float* th = (const float*)d_in[2];

    f32x4* out_re = (f32x4*)d_out;
    f32x4* out_im = out_re + ((size_t)NQ_BATCH * NQ_N / 4);

    rx_fillshape_kernel<<<GRID, BLK, 0, stream>>>(sr, si, th, out_re, out_im);
}